// Round 5
// baseline (254.943 us; speedup 1.0000x reference)
//
#include <hip/hip_runtime.h>

#define K_DIM 4096
#define M_DIM 12288
#define KW (K_DIM / 4)      // packed int32 words per weight row = 1024
#define NT_K (K_DIM / 128)  // 32 K-tiles of 128 bytes
#define BM 256
#define BN 256
#define GN 16  // 4096/256 token tiles
#define GM 48  // 12288/256 weight tiles

typedef __attribute__((ext_vector_type(4))) int i32x4;
typedef __attribute__((ext_vector_type(4))) unsigned int u32x4;

__device__ __forceinline__ int quant1(float v, float qs) {
  float r = rintf(v * qs);  // round half-to-even, matches jnp.round
  r = fminf(127.f, fmaxf(-128.f, r));
  return (int)r;
}

// unpack one packed byte into 4 code bytes (0..3) at permuted positions
__device__ __forceinline__ unsigned int unp(unsigned int uv) {
  return ((uv >> 6) | (uv << 4) | (uv << 14) | (uv << 24)) & 0x03030303u;
}

// One block per token row: absmax -> int8 quantize (k-permuted pack) + rowsum.
__global__ __launch_bounds__(256) void quant_kernel(const float* __restrict__ x,
                                                    unsigned int* __restrict__ xq,
                                                    float2* __restrict__ scales) {
  const int n = blockIdx.x;
  const int t = threadIdx.x;
  const float* __restrict__ row = x + (size_t)n * K_DIM;
  const float4* __restrict__ row4 = (const float4*)row;

  float am = 0.f;
#pragma unroll
  for (int p = 0; p < 4; ++p) {
    float4 v = row4[t + 256 * p];
    am = fmaxf(am, fmaxf(fmaxf(fabsf(v.x), fabsf(v.y)), fmaxf(fabsf(v.z), fabsf(v.w))));
  }
#pragma unroll
  for (int off = 32; off; off >>= 1) am = fmaxf(am, __shfl_xor(am, off, 64));
  __shared__ float redf[4];
  __shared__ int redi[4];
  const int wave = t >> 6, lane = t & 63;
  if (lane == 0) redf[wave] = am;
  __syncthreads();
  am = fmaxf(fmaxf(redf[0], redf[1]), fmaxf(redf[2], redf[3]));
  const float clipped = fmaxf(am, 1e-5f);
  const float qs = 127.0f / clipped;

  int rsum = 0;
#pragma unroll
  for (int p = 0; p < 4; ++p) {
    const int w = t + 256 * p;     // output word index 0..1023
    const int b = w >> 5, j = w & 31;
    const int base = b * 128 + j;  // source k for s=0
    const int q0 = quant1(row[base], qs);
    const int q1 = quant1(row[base + 32], qs);
    const int q2 = quant1(row[base + 64], qs);
    const int q3 = quant1(row[base + 96], qs);
    rsum += q0 + q1 + q2 + q3;
    xq[(size_t)n * KW + w] = (unsigned int)(q0 & 255) | ((unsigned int)(q1 & 255) << 8) |
                             ((unsigned int)(q2 & 255) << 16) | ((unsigned int)(q3 & 255) << 24);
  }
#pragma unroll
  for (int off = 32; off; off >>= 1) rsum += __shfl_xor(rsum, off, 64);
  if (lane == 0) redi[wave] = rsum;
  __syncthreads();
  if (t == 0)
    scales[n] = make_float2(clipped * (1.0f / 127.0f),
                            (float)(redi[0] + redi[1] + redi[2] + redi[3]));
}

// Pre-unpack weights into FRAGMENT-TILED layout so GEMM B-loads are coalesced
// global->reg 1-KiB wave loads. 16-B chunk address (in u32x4 units):
//   rt*4096 + kb*128 + ks*64 + hi*16 + lo
// holds row rt*16+lo, k' bytes kb*128 + (ks*4+hi)*16 .. +16 (codes 0..3).
// Lanes lo=0..15 of 16 consecutive threads write 256 B contiguous (coalesced).
__global__ __launch_bounds__(256) void unpack_tiled(const int* __restrict__ in,
                                                    u32x4* __restrict__ outp) {
  const int total = M_DIM * 256;  // number of 16-B output chunks
  int t = blockIdx.x * 256 + threadIdx.x;
  const int stride = gridDim.x * 256;
  for (; t < total; t += stride) {
    const int lo = t & 15;
    const int cc = (t >> 4) & 255;  // kb*8 + c8
    const int rt = t >> 12;
    const int r = rt * 16 + lo;
    const i32x4 v = *(const i32x4*)(in + (size_t)r * KW + cc * 4);
    u32x4 u = {unp((unsigned int)v[0]), unp((unsigned int)v[1]), unp((unsigned int)v[2]),
               unp((unsigned int)v[3])};
    const int kb = cc >> 3, c8 = cc & 7;
    outp[rt * 4096 + kb * 128 + (c8 >> 2) * 64 + (c8 & 3) * 16 + lo] = u;
  }
}

#define LOAD_B(dst, kb)                                                                   \
  {                                                                                       \
    _Pragma("unroll") for (int q_ = 0; q_ < 8; ++q_) dst[q_] =                            \
        *(const i32x4*)(bBase + (q_ & 3) * 65536 + (q_ >> 2) * 1024 + (size_t)(kb) * 2048); \
  }

#define COMPUTE(Ab, bS)                                                                   \
  {                                                                                       \
    _Pragma("unroll") for (int ih_ = 0; ih_ < 2; ++ih_) {                                 \
      _Pragma("unroll") for (int ks_ = 0; ks_ < 2; ++ks_) {                               \
        i32x4 af[4];                                                                      \
        _Pragma("unroll") for (int i_ = 0; i_ < 4; ++i_) af[i_] =                         \
            *(const i32x4*)((Ab) + (aoff[ih_ * 4 + i_] ^ (ks_ << 6)));                    \
        __builtin_amdgcn_s_setprio(1);                                                    \
        _Pragma("unroll") for (int i_ = 0; i_ < 4; ++i_)                                  \
            _Pragma("unroll") for (int j_ = 0; j_ < 4; ++j_) acc[ih_ * 4 + i_][j_] =      \
                __builtin_amdgcn_mfma_i32_16x16x64_i8(af[i_], bS[ks_ * 4 + j_],           \
                                                      acc[ih_ * 4 + i_][j_], 0, 0, 0);    \
        __builtin_amdgcn_s_setprio(0);                                                    \
      }                                                                                   \
    }                                                                                     \
  }

// 256x256 tile, BK=128 B, 8 waves (2 row-halves x 4 col-quarters). A: LDS
// double-buffered (64 KiB total), gload_lds + XOR swizzle (PMC-verified
// conflict-free). B: DIRECT global->reg from fragment-tiled wu2, double-
// buffered one tile ahead (bX/bY). Counted vmcnt(12), XCD block swizzle.
__global__ __launch_bounds__(512, 2) void bitgemm256(const unsigned char* __restrict__ xq,
                                                     const unsigned char* __restrict__ wu2,
                                                     const float2* __restrict__ scales,
                                                     const float* __restrict__ wsp,
                                                     float* __restrict__ out) {
  __shared__ __align__(16) unsigned char lds[65536];  // [2][256][128] A only

  const int tid = threadIdx.x;
  const int l = tid & 63;
  const int w = tid >> 6;  // 0..7
  const int wm = w >> 2;   // row half 0..1
  const int wn = w & 3;    // col quarter 0..3

  // XCD swizzle: 768 blocks (%8==0 -> bijective), bm-major within each XCD
  const int cpx = gridDim.x >> 3;
  const int swz = (blockIdx.x & 7) * cpx + (blockIdx.x >> 3);
  const int bn = swz & (GN - 1);  // token tile
  const int bm = swz >> 4;        // weight tile

  // A staging: thread -> (row in 64-group, 16B chunk), source pre-swizzled
  const int srow = tid >> 3;
  const int schunk = (tid & 7) ^ (srow & 7);
  const unsigned char* aSrc = xq + (size_t)(bn * BM) * K_DIM + (size_t)srow * K_DIM + (schunk << 4);
  const int ldsDst = tid * 16;

  // B direct-load base: fragment-tiled, lane-linear
  const unsigned char* bBase = wu2 + (((size_t)(bm * 16 + wn * 4) * 4096 + l) << 4);

  // A fragment read byte-offsets; ks=1 toggles bit 6 (chunk+4 pre-swizzle)
  int aoff[8];
#pragma unroll
  for (int i = 0; i < 8; ++i) {
    const int r = wm * 128 + i * 16 + (l & 15);
    aoff[i] = r * 128 + (((l >> 4) ^ (r & 7)) << 4);
  }

  i32x4 acc[8][4];
#pragma unroll
  for (int i = 0; i < 8; ++i)
#pragma unroll
    for (int j = 0; j < 4; ++j) acc[i][j] = (i32x4){0, 0, 0, 0};

  auto stageA = [&](int buf, int kb) {
    unsigned char* ad = lds + buf * 32768 + ldsDst;
    const unsigned char* as_ = aSrc + kb * 128;
#pragma unroll
    for (int q = 0; q < 4; ++q)
      __builtin_amdgcn_global_load_lds(
          (const __attribute__((address_space(1))) void*)(as_ + (size_t)q * 64 * K_DIM),
          (__attribute__((address_space(3))) void*)(ad + q * 8192), 16, 0, 0);
  };

  i32x4 bX[8], bY[8];
  const unsigned char* A0 = lds;
  const unsigned char* A1 = lds + 32768;

  stageA(0, 0);
  LOAD_B(bX, 0);
  for (int kb2 = 0; kb2 < NT_K / 2; ++kb2) {
    const int e = kb2 * 2;
    // ---- even tile e: A0, bX ----
    stageA(1, e + 1);
    LOAD_B(bY, e + 1);
    asm volatile("s_waitcnt vmcnt(12)" ::: "memory");  // tile e's 12 landed; e+1's in flight
    __builtin_amdgcn_s_barrier();
    COMPUTE(A0, bX);
    __builtin_amdgcn_s_barrier();
    // ---- odd tile e+1: A1, bY ----
    if (kb2 < NT_K / 2 - 1) {
      stageA(0, e + 2);
      LOAD_B(bX, e + 2);
      asm volatile("s_waitcnt vmcnt(12)" ::: "memory");
    } else {
      asm volatile("s_waitcnt vmcnt(0)" ::: "memory");
    }
    __builtin_amdgcn_s_barrier();
    COMPUTE(A1, bY);
    __builtin_amdgcn_s_barrier();
  }

  // epilogue: out = (dot_codes - rowsum) * weight_scale * act_scale
  const float wsc = wsp[0];
#pragma unroll
  for (int i = 0; i < 8; ++i) {
#pragma unroll
    for (int r = 0; r < 4; ++r) {
      const int n = bn * BM + wm * 128 + i * 16 + ((l >> 4) << 2) + r;
      const float2 sc = scales[n];
      const float f = wsc * sc.x;
      float* orow = out + (size_t)n * M_DIM + bm * BN + wn * 64 + (l & 15);
#pragma unroll
      for (int j = 0; j < 4; ++j) orow[j * 16] = ((float)acc[i][j][r] - sc.y) * f;
    }
  }
}

extern "C" void kernel_launch(void* const* d_in, const int* in_sizes, int n_in,
                              void* d_out, int out_size, void* d_ws, size_t ws_size,
                              hipStream_t stream) {
  const float* x = (const float*)d_in[0];
  const int* wp = (const int*)d_in[1];
  const float* wsp = (const float*)d_in[2];
  float* out = (float*)d_out;
  const int N = in_sizes[0] / K_DIM;  // 4096 tokens

  float2* scales = (float2*)d_ws;                           // N * 8 B
  unsigned int* xq = (unsigned int*)((char*)d_ws + 32768);  // N * KW words
  const size_t xq_bytes = (size_t)N * KW * 4;
  unsigned char* wu2 = (unsigned char*)d_ws + 32768 + xq_bytes;  // M*K tiled codes

  quant_kernel<<<N, 256, 0, stream>>>(x, xq, scales);
  unpack_tiled<<<4096, 256, 0, stream>>>(wp, (u32x4*)wu2);
  const int grid = (N / BM) * GM;  // 16 * 48 = 768
  bitgemm256<<<grid, 512, 0, stream>>>((const unsigned char*)xq, wu2, scales, wsp, out);
}